// Round 11
// baseline (489.545 us; speedup 1.0000x reference)
//
#include <hip/hip_runtime.h>
#include <cstdint>

#define T_SEQ 2048
#define HID   4096
#define NH    32
#define HD    128
#define QKVW  12288   // (32 + 2*32) * 128

typedef float  f32x4  __attribute__((ext_vector_type(4)));
typedef __bf16 bf16x8 __attribute__((ext_vector_type(8)));

// log2(e)/sqrt(128): fold softmax scale + base-2 conversion into Q
#define QSCALE (0.08838834764831845f * 1.4426950408889634f)

__device__ __forceinline__ unsigned short f2bf(float f) {
  unsigned int u = __builtin_bit_cast(unsigned int, f);
  u += 0x7fffu + ((u >> 16) & 1u);          // round-to-nearest-even (inputs finite)
  return (unsigned short)(u >> 16);
}
__device__ __forceinline__ float bf2f(unsigned short u) {
  return __builtin_bit_cast(float, (unsigned int)u << 16);
}

// async global->LDS, 16B per lane. LDS dest is wave-uniform base + lane*16.
__device__ __forceinline__ void gload_lds16(const void* gptr, void* lptr) {
  __builtin_amdgcn_global_load_lds(
      (const __attribute__((address_space(1))) unsigned int*)(unsigned long long)(uintptr_t)gptr,
      (__attribute__((address_space(3))) unsigned int*)(unsigned int)(uintptr_t)lptr,
      16, 0, 0);
}

#define SB __builtin_amdgcn_sched_barrier(0)

// ---------------------------------------------------------------- f32 -> bf16
__global__ __launch_bounds__(256) void cast_bf16(const float* __restrict__ in,
                                                 unsigned short* __restrict__ out,
                                                 int n4) {
  int i = blockIdx.x * 256 + threadIdx.x;
  int stride = gridDim.x * 256;
  for (; i < n4; i += stride) {
    float4 v = ((const float4*)in)[i];
    ushort4 o;
    o.x = f2bf(v.x); o.y = f2bf(v.y); o.z = f2bf(v.z); o.w = f2bf(v.w);
    ((ushort4*)out)[i] = o;
  }
}

// ------------------------------------------------- 2-phase GEMM (R3): C = A*B^T
// BM=128, BN=256, BK=64. 512 threads = 8 waves (2M x 4N), 64x64 per wave.
// Used for GEMM2 (256 blocks = one perfect CU round). f32 C output.
__global__ __launch_bounds__(512, 2) void gemm_bt(const unsigned short* __restrict__ Ag,
                                                  const unsigned short* __restrict__ Bg,
                                                  float* __restrict__ C,
                                                  int M, int N, int K, int MT) {
  __shared__ unsigned short As_[2][128 * 64];
  __shared__ unsigned short Bs_[2][256 * 64];
  const int tid  = threadIdx.x;
  const int lane = tid & 63;
  const int w    = tid >> 6;
  const int wm   = w >> 2;
  const int wn   = w & 3;
  const int l15  = lane & 15;
  const int lg   = lane >> 4;

  const int nwg = gridDim.x;
  const int cpx = nwg >> 3;
  const int swz = (blockIdx.x & 7) * cpx + (blockIdx.x >> 3);
  const int bm  = (swz % MT) * 128;
  const int bn  = (swz / MT) * 256;
  const int nk  = K >> 6;

#define STAGE_A(buf, kt_) do {                                                   \
    const unsigned short* _s = Ag + (size_t)bm * K + (size_t)(kt_) * 64;         \
    _Pragma("unroll")                                                            \
    for (int _u = 0; _u < 2; ++_u) {                                             \
      const int _cid = _u * 512 + tid;                                           \
      const int _r = _cid >> 3, _ch = _cid & 7;                                  \
      gload_lds16(_s + (size_t)_r * K + ((_ch ^ (_r & 7)) * 8),                  \
                  &As_[buf][(_u * 512 + w * 64) * 8]);                           \
    } } while (0)

#define STAGE_B(buf, kt_) do {                                                   \
    const unsigned short* _s = Bg + (size_t)bn * K + (size_t)(kt_) * 64;         \
    _Pragma("unroll")                                                            \
    for (int _u = 0; _u < 4; ++_u) {                                             \
      const int _cid = _u * 512 + tid;                                           \
      const int _r = _cid >> 3, _ch = _cid & 7;                                  \
      gload_lds16(_s + (size_t)_r * K + ((_ch ^ (_r & 7)) * 8),                  \
                  &Bs_[buf][(_u * 512 + w * 64) * 8]);                           \
    } } while (0)

  f32x4 acc[4][4] = {};

  STAGE_A(0, 0);
  STAGE_B(0, 0);
  if (nk > 1) {
    STAGE_B(1, 1);
    asm volatile("s_waitcnt vmcnt(4)" ::: "memory");
  } else {
    asm volatile("s_waitcnt vmcnt(0)" ::: "memory");
  }
  __builtin_amdgcn_s_barrier();

  for (int t = 0; t < nk; ++t) {
    const int cur = t & 1;
    bf16x8 bfr[4][2];
#pragma unroll
    for (int n = 0; n < 4; ++n)
#pragma unroll
      for (int kk = 0; kk < 2; ++kk) {
        const int r = wn * 64 + n * 16 + l15;
        bfr[n][kk] = *(const bf16x8*)&Bs_[cur][r * 64 + (((kk * 4 + lg) ^ (r & 7)) * 8)];
      }
    bf16x8 a0[2][2];
#pragma unroll
    for (int mi = 0; mi < 2; ++mi)
#pragma unroll
      for (int kk = 0; kk < 2; ++kk) {
        const int r = wm * 64 + mi * 16 + l15;
        a0[mi][kk] = *(const bf16x8*)&As_[cur][r * 64 + (((kk * 4 + lg) ^ (r & 7)) * 8)];
      }
    if (t + 1 < nk) STAGE_A(cur ^ 1, t + 1);
    __builtin_amdgcn_s_barrier();
    __builtin_amdgcn_s_setprio(1);
#pragma unroll
    for (int mi = 0; mi < 2; ++mi)
#pragma unroll
      for (int n = 0; n < 4; ++n)
#pragma unroll
        for (int kk = 0; kk < 2; ++kk)
          acc[mi][n] = __builtin_amdgcn_mfma_f32_16x16x32_bf16(a0[mi][kk], bfr[n][kk], acc[mi][n], 0, 0, 0);
    __builtin_amdgcn_s_setprio(0);
    __builtin_amdgcn_s_barrier();

    bf16x8 a1[2][2];
#pragma unroll
    for (int mi = 0; mi < 2; ++mi)
#pragma unroll
      for (int kk = 0; kk < 2; ++kk) {
        const int r = wm * 64 + (2 + mi) * 16 + l15;
        a1[mi][kk] = *(const bf16x8*)&As_[cur][r * 64 + (((kk * 4 + lg) ^ (r & 7)) * 8)];
      }
    if (t + 2 < nk) STAGE_B(cur, t + 2);
    __builtin_amdgcn_s_barrier();
    __builtin_amdgcn_s_setprio(1);
#pragma unroll
    for (int mi = 0; mi < 2; ++mi)
#pragma unroll
      for (int n = 0; n < 4; ++n)
#pragma unroll
        for (int kk = 0; kk < 2; ++kk)
          acc[2 + mi][n] = __builtin_amdgcn_mfma_f32_16x16x32_bf16(a1[mi][kk], bfr[n][kk], acc[2 + mi][n], 0, 0, 0);
    __builtin_amdgcn_s_setprio(0);
    if (t + 1 < nk) {
      if (t + 2 < nk) asm volatile("s_waitcnt vmcnt(4)" ::: "memory");
      else            asm volatile("s_waitcnt vmcnt(0)" ::: "memory");
      __builtin_amdgcn_sched_barrier(0);
    }
    __builtin_amdgcn_s_barrier();
  }
#undef STAGE_A
#undef STAGE_B

#pragma unroll
  for (int m = 0; m < 4; ++m)
#pragma unroll
    for (int i = 0; i < 4; ++i) {
      const int row = bm + wm * 64 + m * 16 + lg * 4 + i;
#pragma unroll
      for (int n = 0; n < 4; ++n)
        C[(size_t)row * N + bn + wn * 64 + n * 16 + l15] = acc[m][n][i];
    }
}

// ------- 256x192 GEMM1, (4M x 2N) waves, 2-cluster pipelined K-loop, bf16 C
// (R10 structure, 206us / 44% MfmaUtil — local ceiling for this family)
__global__ __launch_bounds__(512, 2) void gemm_bt8(const unsigned short* __restrict__ Ag,
                                                   const unsigned short* __restrict__ Bg,
                                                   unsigned short* __restrict__ C,
                                                   int M, int N, int K, int MT) {
  __shared__ unsigned short As_[2][256 * 64];   // 32 KB x2
  __shared__ unsigned short Bs_[2][192 * 64];   // 24 KB x2  (112 KB total)
  const int tid  = threadIdx.x;
  const int lane = tid & 63;
  const int w    = tid >> 6;
  const int wm   = w & 3;         // 0..3  (M quarter, 64 rows)
  const int wn   = w >> 2;        // 0..1  (N half, 96 cols)
  const int l15  = lane & 15;
  const int lg   = lane >> 4;
  const int sw   = l15 & 7;

  const int cpx = gridDim.x >> 3;
  const int swz = (blockIdx.x & 7) * cpx + (blockIdx.x >> 3);
  const int bm  = (swz % MT) * 256;
  const int bn  = (swz / MT) * 192;
  const int nk  = K >> 6;

  const unsigned short* Abase = Ag + (size_t)bm * K;
  const unsigned short* Bbase = Bg + (size_t)bn * K;

#define SG(ldsbase, gbase, kt_, u_) do {                                        \
    const int _cid = (u_) * 512 + tid;                                          \
    const int _r = _cid >> 3, _ch = _cid & 7;                                   \
    gload_lds16((gbase) + (size_t)_r * K + (size_t)(kt_) * 64 +                 \
                    ((_ch ^ (_r & 7)) * 8),                                     \
                (void*)((char*)(ldsbase) + _cid * 16));                         \
  } while (0)
#define STAGE(abuf, bbuf, kt_) do {                                             \
    SG(abuf, Abase, kt_, 0); SG(abuf, Abase, kt_, 1);                           \
    SG(abuf, Abase, kt_, 2); SG(abuf, Abase, kt_, 3);                           \
    SG(bbuf, Bbase, kt_, 0); SG(bbuf, Bbase, kt_, 1);                           \
    SG(bbuf, Bbase, kt_, 2);                                                    \
  } while (0)

#define RD(base, r, kk)                                                          \
  (*(const bf16x8*)((const char*)(base) + (r) * 128 + ((((kk) * 4 + lg) ^ sw) * 16)))

#define MFMA24(afr, bfr) do {                                                    \
    _Pragma("unroll")                                                            \
    for (int _m = 0; _m < 4; ++_m)                                               \
      _Pragma("unroll")                                                          \
      for (int _n = 0; _n < 6; ++_n)                                             \
        acc[_m][_n] = __builtin_amdgcn_mfma_f32_16x16x32_bf16(                   \
            afr[_m], bfr[_n], acc[_m][_n], 0, 0, 0);                             \
  } while (0)

  f32x4 acc[4][6] = {};

  STAGE(As_[0], Bs_[0], 0);
  if (nk > 1) {
    STAGE(As_[1], Bs_[1], 1);
    asm volatile("s_waitcnt vmcnt(7)" ::: "memory");
  } else {
    asm volatile("s_waitcnt vmcnt(0)" ::: "memory");
  }
  SB;
  __builtin_amdgcn_s_barrier();

  for (int t = 0; t < nk; ++t) {
    const int cur = t & 1;
    const unsigned short* As = As_[cur];
    const unsigned short* Bs = Bs_[cur];
    bf16x8 a0[4], a1[4], b0[6], b1[6];

#pragma unroll
    for (int m = 0; m < 4; ++m) a0[m] = RD(As, wm * 64 + m * 16 + l15, 0);
#pragma unroll
    for (int n = 0; n < 6; ++n) b0[n] = RD(Bs, wn * 96 + n * 16 + l15, 0);
    SB;
#pragma unroll
    for (int m = 0; m < 4; ++m) a1[m] = RD(As, wm * 64 + m * 16 + l15, 1);
#pragma unroll
    for (int n = 0; n < 6; ++n) b1[n] = RD(Bs, wn * 96 + n * 16 + l15, 1);
    SB;
    asm volatile("s_waitcnt lgkmcnt(10)" ::: "memory");
    SB;
    __builtin_amdgcn_s_setprio(1);
    MFMA24(a0, b0);
    __builtin_amdgcn_s_setprio(0);
    SB;
    asm volatile("s_waitcnt lgkmcnt(0)" ::: "memory");
    SB;
    __builtin_amdgcn_s_barrier();
    if (t + 2 < nk) STAGE(As_[cur], Bs_[cur], t + 2);
    SB;
    __builtin_amdgcn_s_setprio(1);
    MFMA24(a1, b1);
    __builtin_amdgcn_s_setprio(0);
    if (t + 1 < nk) {
      if (t + 2 < nk) asm volatile("s_waitcnt vmcnt(7)" ::: "memory");
      else            asm volatile("s_waitcnt vmcnt(0)" ::: "memory");
      SB;
      __builtin_amdgcn_s_barrier();
    }
  }
#undef SG
#undef STAGE
#undef RD
#undef MFMA24

#pragma unroll
  for (int m = 0; m < 4; ++m)
#pragma unroll
    for (int i = 0; i < 4; ++i) {
      const int row = bm + wm * 64 + m * 16 + lg * 4 + i;
#pragma unroll
      for (int n = 0; n < 6; ++n)
        C[(size_t)row * N + bn + wn * 96 + n * 16 + l15] = f2bf(acc[m][n][i]);
    }
}

// ---------------------------------------- LayerNorm + RoPE + split/cast kernel
__global__ __launch_bounds__(256) void norm_rope(const unsigned short* __restrict__ qkv,
                                                 const float* __restrict__ qw,
                                                 const float* __restrict__ qb,
                                                 const float* __restrict__ kw,
                                                 const float* __restrict__ kb,
                                                 unsigned short* __restrict__ q,
                                                 unsigned short* __restrict__ k) {
  const int t    = blockIdx.x;
  const int tid  = threadIdx.x;
  const int lane = tid & 63;
  const int w    = tid >> 6;
  const float invf = exp2f(-(float)lane * (13.287712379549449f / 64.0f)); // 10000^(-lane/64)
  const float ang  = (float)t * invf;
  const float c = cosf(ang), s = sinf(ang);
  const unsigned short* row = qkv + (size_t)t * QKVW;

#pragma unroll 1
  for (int sel = 0; sel < 2; ++sel) {
    const unsigned short* src = row + sel * HID;
    const float* wgt = sel ? kw : qw;
    const float* bia = sel ? kb : qb;
    unsigned short* dst = sel ? k : q;
    const float oscale = sel ? 1.0f : QSCALE;
    for (int h = w; h < NH; h += 4) {
      const unsigned short* x = src + h * HD;
      float x1 = bf2f(x[lane]), x2 = bf2f(x[lane + 64]);
      float sum = x1 + x2, ss = x1 * x1 + x2 * x2;
#pragma unroll
      for (int m = 1; m < 64; m <<= 1) {
        sum += __shfl_xor(sum, m, 64);
        ss  += __shfl_xor(ss, m, 64);
      }
      const float mu  = sum * (1.0f / 128.0f);
      const float var = ss * (1.0f / 128.0f) - mu * mu;
      const float r   = rsqrtf(var + 1e-5f);
      const float n1  = (x1 - mu) * r * wgt[h * HD + lane]      + bia[h * HD + lane];
      const float n2  = (x2 - mu) * r * wgt[h * HD + lane + 64] + bia[h * HD + lane + 64];
      const float o1  = (n1 * c - n2 * s) * oscale;
      const float o2  = (n2 * c + n1 * s) * oscale;
      dst[(size_t)t * HID + h * HD + lane]      = f2bf(o1);
      dst[(size_t)t * HID + h * HD + lane + 64] = f2bf(o2);
    }
  }
}

// --------------------------- V transpose: [T][stride=QKVW] slice ->[H][D][T]
__global__ __launch_bounds__(256) void transpose_v(const unsigned short* __restrict__ v,
                                                   unsigned short* __restrict__ vt) {
  __shared__ unsigned short tile[64][65];
  const int h  = blockIdx.z;
  const int tt = blockIdx.x * 64;
  const int dd = blockIdx.y * 64;
  const int tid = threadIdx.x;
#pragma unroll
  for (int p = 0; p < 4; ++p) {
    int idx = p * 256 + tid;
    int r = idx >> 4, c4 = idx & 15;
    ushort4 val = *(const ushort4*)&v[(size_t)(tt + r) * QKVW + h * HD + dd + c4 * 4];
    tile[r][c4 * 4 + 0] = val.x;
    tile[r][c4 * 4 + 1] = val.y;
    tile[r][c4 * 4 + 2] = val.z;
    tile[r][c4 * 4 + 3] = val.w;
  }
  __syncthreads();
#pragma unroll
  for (int p = 0; p < 4; ++p) {
    int idx = p * 256 + tid;
    int r = idx >> 4, c4 = idx & 15;
    ushort4 o;
    o.x = tile[c4 * 4 + 0][r];
    o.y = tile[c4 * 4 + 1][r];
    o.z = tile[c4 * 4 + 2][r];
    o.w = tile[c4 * 4 + 3][r];
    *(ushort4*)&vt[((size_t)h * HD + dd + r) * T_SEQ + tt + c4 * 4] = o;
  }
}

// -------------------------------------------------- causal flash attention
// QBLK=128: 4 waves x 32 q-rows (2 fragments of 16). K/V fragments read ONCE
// per wave feed BOTH q-fragments' MFMAs (intensity 0.94 -> 1.78 MFMA/ds_read).
// KVBLK=64, double-buffered swizzled K/V, per-wave P in LDS (2 frag buffers).
// Pairing (j, 15-j) over 16 q-tiles of 128 rows -> 34 uniform iters/block.
// Grid 8 x 32 = 256 blocks = 1 per CU. LDS = 80 KB.
__global__ __launch_bounds__(256) void attn_fwd(const unsigned short* __restrict__ Q,
                                                const unsigned short* __restrict__ K,
                                                const unsigned short* __restrict__ VT,
                                                unsigned short* __restrict__ O) {
  __shared__ unsigned short Ks[2][64 * 128];   // [kv][d], swizzled  (32 KB)
  __shared__ unsigned short Vs[2][128 * 64];   // [d][kv], swizzled  (32 KB)
  __shared__ unsigned short Ps[4][2][16 * 64]; // per-wave, per-frag (16 KB)
  const int h    = blockIdx.y;
  const int pr   = blockIdx.x;                 // 0..7
  const int tid  = threadIdx.x;
  const int lane = tid & 63;
  const int w    = tid >> 6;
  const int l15  = lane & 15;
  const int lg   = lane >> 4;
  const int sw   = l15 & 7;

#pragma unroll 1
  for (int half = 0; half < 2; ++half) {
    const int jt    = half ? (15 - pr) : pr;    // 128-row q-tile index
    const int qbase = jt * 128 + w * 32;

    bf16x8 qf[2][4];
#pragma unroll
    for (int f = 0; f < 2; ++f)
#pragma unroll
      for (int kk = 0; kk < 4; ++kk)
        qf[f][kk] = *(const bf16x8*)&Q[(size_t)(qbase + f * 16 + l15) * HID + h * HD + kk * 32 + lg * 8];

    f32x4 o[2][8] = {};
    float mrow[2][4], lrow[2][4];
#pragma unroll
    for (int f = 0; f < 2; ++f)
#pragma unroll
      for (int i = 0; i < 4; ++i) { mrow[f][i] = -1e30f; lrow[f][i] = 0.0f; }

    const int nkt = 2 * (jt + 1);

    // prologue: stage kv-tile 0 into buffer 0
    {
#pragma unroll
      for (int p = 0; p < 4; ++p) {
        const int c  = p * 256 + tid;
        const int kr = c >> 4, kc = c & 15;
        gload_lds16(&K[(size_t)kr * HID + h * HD + ((kc ^ (kr & 7)) * 8)],
                    &Ks[0][(p * 256 + w * 64) * 8]);
        const int vr = c >> 3, vc = c & 7;
        gload_lds16(&VT[((size_t)h * HD + vr) * T_SEQ + ((vc ^ (vr & 7)) * 8)],
                    &Vs[0][(p * 256 + w * 64) * 8]);
      }
    }
    __syncthreads();

#pragma unroll 1
    for (int kt = 0; kt < nkt; ++kt) {
      const int cur = kt & 1;
      if (kt + 1 < nkt) {
        const int k0 = (kt + 1) * 64;
#pragma unroll
        for (int p = 0; p < 4; ++p) {
          const int c  = p * 256 + tid;
          const int kr = c >> 4, kc = c & 15;
          gload_lds16(&K[(size_t)(k0 + kr) * HID + h * HD + ((kc ^ (kr & 7)) * 8)],
                      &Ks[cur ^ 1][(p * 256 + w * 64) * 8]);
          const int vr = c >> 3, vc = c & 7;
          gload_lds16(&VT[((size_t)h * HD + vr) * T_SEQ + k0 + ((vc ^ (vr & 7)) * 8)],
                      &Vs[cur ^ 1][(p * 256 + w * 64) * 8]);
        }
      }
      const unsigned short* ksb = Ks[cur];
      const unsigned short* vsb = Vs[cur];

      // QK^T both frags: each K fragment read feeds 2 MFMAs
      f32x4 sfr[2][4] = {};
#pragma unroll
      for (int n = 0; n < 4; ++n)
#pragma unroll
        for (int kk = 0; kk < 4; ++kk) {
          bf16x8 kf = *(const bf16x8*)&ksb[(n * 16 + l15) * 128 + ((kk * 4 + lg) ^ sw) * 8];
          sfr[0][n] = __builtin_amdgcn_mfma_f32_16x16x32_bf16(qf[0][kk], kf, sfr[0][n], 0, 0, 0);
          sfr[1][n] = __builtin_amdgcn_mfma_f32_16x16x32_bf16(qf[1][kk], kf, sfr[1][n], 0, 0, 0);
        }

      if (kt >= 2 * jt) {  // diagonal region: global-coordinate causal mask
#pragma unroll
        for (int f = 0; f < 2; ++f)
#pragma unroll
          for (int n = 0; n < 4; ++n)
#pragma unroll
            for (int i = 0; i < 4; ++i)
              if (kt * 64 + n * 16 + l15 > qbase + f * 16 + lg * 4 + i) sfr[f][n][i] = -1e30f;
      }

      // online softmax (base-2 domain), per frag
#pragma unroll
      for (int f = 0; f < 2; ++f) {
        float escale[4];
#pragma unroll
        for (int i = 0; i < 4; ++i) {
          float mx = fmaxf(fmaxf(sfr[f][0][i], sfr[f][1][i]), fmaxf(sfr[f][2][i], sfr[f][3][i]));
          mx = fmaxf(mx, __shfl_xor(mx, 1, 64));
          mx = fmaxf(mx, __shfl_xor(mx, 2, 64));
          mx = fmaxf(mx, __shfl_xor(mx, 4, 64));
          mx = fmaxf(mx, __shfl_xor(mx, 8, 64));
          const float mnew = fmaxf(mrow[f][i], mx);
          escale[i] = exp2f(mrow[f][i] - mnew);
          mrow[f][i] = mnew;
          const int prow = lg * 4 + i;
          float rs = 0.0f;
#pragma unroll
          for (int n = 0; n < 4; ++n) {
            const float p = exp2f(sfr[f][n][i] - mnew);
            rs += p;
            Ps[w][f][prow * 64 + (((2 * n + (l15 >> 3)) ^ (prow & 7)) * 8) + sw] = f2bf(p);
          }
          rs += __shfl_xor(rs, 1, 64);
          rs += __shfl_xor(rs, 2, 64);
          rs += __shfl_xor(rs, 4, 64);
          rs += __shfl_xor(rs, 8, 64);
          lrow[f][i] = lrow[f][i] * escale[i] + rs;
        }
#pragma unroll
        for (int fd = 0; fd < 8; ++fd)
#pragma unroll
          for (int i = 0; i < 4; ++i) o[f][fd][i] *= escale[i];
      }

      // P is wave-private: drain LDS writes only
      asm volatile("s_waitcnt lgkmcnt(0)" ::: "memory");
      __builtin_amdgcn_sched_barrier(0);

      bf16x8 pf[2][2];
#pragma unroll
      for (int f = 0; f < 2; ++f)
#pragma unroll
        for (int kk = 0; kk < 2; ++kk)
          pf[f][kk] = *(const bf16x8*)&Ps[w][f][l15 * 64 + ((kk * 4 + lg) ^ sw) * 8];

      // PV fused over frags: each V fragment read feeds 2 MFMAs
#pragma unroll
      for (int fd = 0; fd < 8; ++fd)
#pragma unroll
        for (int kk = 0; kk < 2; ++kk) {
          bf16x8 vf = *(const bf16x8*)&vsb[(fd * 16 + l15) * 64 + ((kk * 4 + lg) ^ sw) * 8];
          o[0][fd] = __builtin_amdgcn_mfma_f32_16x16x32_bf16(pf[0][kk], vf, o[0][fd], 0, 0, 0);
          o[1][fd] = __builtin_amdgcn_mfma_f32_16x16x32_bf16(pf[1][kk], vf, o[1][fd], 0, 0, 0);
        }

      __syncthreads();  // buf[cur] reads done; next-tile stages drained
    }

#pragma unroll
    for (int f = 0; f < 2; ++f)
#pragma unroll
      for (int i = 0; i < 4; ++i) {
        const float inv = 1.0f / lrow[f][i];
        const int trow = qbase + f * 16 + lg * 4 + i;
#pragma unroll
        for (int fd = 0; fd < 8; ++fd)
          O[(size_t)trow * HID + h * HD + fd * 16 + l15] = f2bf(o[f][fd][i] * inv);
      }
  }
}

// ------------------------------------------------------------------- launch
extern "C" void kernel_launch(void* const* d_in, const int* in_sizes, int n_in,
                              void* d_out, int out_size, void* d_ws, size_t ws_size,
                              hipStream_t stream) {
  const float* hidden = (const float*)d_in[1];
  const float* w_qkv  = (const float*)d_in[2];
  const float* w_o    = (const float*)d_in[3];
  const float* qw     = (const float*)d_in[4];
  const float* qb     = (const float*)d_in[5];
  const float* kw     = (const float*)d_in[6];
  const float* kb     = (const float*)d_in[7];

  char* ws = (char*)d_ws;
  // region A (100663296 B): w_qkv_bf16 during GEMM1; then attn_bf16 + w_o_bf16
  unsigned short* wqkv_bf = (unsigned short*)(ws + 0);
  unsigned short* attn_bf = (unsigned short*)(ws + 0);
  unsigned short* wo_bf   = (unsigned short*)(ws + 16777216);
  // region B (16777216 B): hidden_bf16 during GEMM1; then vt
  unsigned short* hid_bf  = (unsigned short*)(ws + 100663296);
  unsigned short* vt_bf   = (unsigned short*)(ws + 100663296);
  // region C: qkv bf16 [T][12288] (50331648 B); V slice stays in place
  unsigned short* qkv_bf  = (unsigned short*)(ws + 117440512);
  // region D: q,k bf16
  unsigned short* q_bf    = (unsigned short*)(ws + 167772160);
  unsigned short* k_bf    = (unsigned short*)(ws + 184549376);

  cast_bf16<<<2048, 256, 0, stream>>>(hidden, hid_bf, (T_SEQ * HID) / 4);
  cast_bf16<<<2048, 256, 0, stream>>>(w_qkv, wqkv_bf, (QKVW * HID) / 4);
  // GEMM1: M=2048 (MT=8), N=12288 -> 8 x 64 = 512 blocks = 2 perfect CU rounds
  gemm_bt8<<<512, 512, 0, stream>>>(hid_bf, wqkv_bf, qkv_bf, T_SEQ, QKVW, HID, 8);
  cast_bf16<<<2048, 256, 0, stream>>>(w_o, wo_bf, (HID * HID) / 4);
  norm_rope<<<T_SEQ, 256, 0, stream>>>(qkv_bf, qw, qb, kw, kb, q_bf, k_bf);
  transpose_v<<<dim3(T_SEQ / 64, HD / 64, NH), 256, 0, stream>>>(qkv_bf + 2 * HID, vt_bf);
  // attn: QBLK=128, pairing (j, 15-j) -> 8 x 32 = 256 blocks (1/CU)
  attn_fwd<<<dim3(8, NH), 256, 0, stream>>>(q_bf, k_bf, vt_bf, attn_bf);
  // GEMM2: 2-phase kernel, M=2048 (MT=16), N=4096 -> 256 blocks (1 full round)
  gemm_bt<<<256, 512, 0, stream>>>(attn_bf, wo_bf, (float*)d_out, T_SEQ, HID, HID, 16);
}

// Round 12
// 456.949 us; speedup vs baseline: 1.0713x; 1.0713x over previous
//
#include <hip/hip_runtime.h>
#include <cstdint>

#define T_SEQ 2048
#define HID   4096
#define NH    32
#define HD    128
#define QKVW  12288   // (32 + 2*32) * 128

typedef float  f32x4  __attribute__((ext_vector_type(4)));
typedef __bf16 bf16x8 __attribute__((ext_vector_type(8)));

// log2(e)/sqrt(128): fold softmax scale + base-2 conversion into Q
#define QSCALE (0.08838834764831845f * 1.4426950408889634f)

__device__ __forceinline__ unsigned short f2bf(float f) {
  unsigned int u = __builtin_bit_cast(unsigned int, f);
  u += 0x7fffu + ((u >> 16) & 1u);          // round-to-nearest-even (inputs finite)
  return (unsigned short)(u >> 16);
}
__device__ __forceinline__ float bf2f(unsigned short u) {
  return __builtin_bit_cast(float, (unsigned int)u << 16);
}

// async global->LDS, 16B per lane. LDS dest is wave-uniform base + lane*16.
__device__ __forceinline__ void gload_lds16(const void* gptr, void* lptr) {
  __builtin_amdgcn_global_load_lds(
      (const __attribute__((address_space(1))) unsigned int*)(unsigned long long)(uintptr_t)gptr,
      (__attribute__((address_space(3))) unsigned int*)(unsigned int)(uintptr_t)lptr,
      16, 0, 0);
}

#define SB __builtin_amdgcn_sched_barrier(0)

// ---------------------------------------------------------------- f32 -> bf16
__global__ __launch_bounds__(256) void cast_bf16(const float* __restrict__ in,
                                                 unsigned short* __restrict__ out,
                                                 int n4) {
  int i = blockIdx.x * 256 + threadIdx.x;
  int stride = gridDim.x * 256;
  for (; i < n4; i += stride) {
    float4 v = ((const float4*)in)[i];
    ushort4 o;
    o.x = f2bf(v.x); o.y = f2bf(v.y); o.z = f2bf(v.z); o.w = f2bf(v.w);
    ((ushort4*)out)[i] = o;
  }
}

// ------- 256x192 GEMM1, (4M x 2N) waves, 2-cluster pipelined K-loop, bf16 C
// (R10 structure, 206us / 44% MfmaUtil)
__global__ __launch_bounds__(512, 2) void gemm_bt8(const unsigned short* __restrict__ Ag,
                                                   const unsigned short* __restrict__ Bg,
                                                   unsigned short* __restrict__ C,
                                                   int M, int N, int K, int MT) {
  __shared__ unsigned short As_[2][256 * 64];   // 32 KB x2
  __shared__ unsigned short Bs_[2][192 * 64];   // 24 KB x2  (112 KB total)
  const int tid  = threadIdx.x;
  const int lane = tid & 63;
  const int w    = tid >> 6;
  const int wm   = w & 3;         // 0..3  (M quarter, 64 rows)
  const int wn   = w >> 2;        // 0..1  (N half, 96 cols)
  const int l15  = lane & 15;
  const int lg   = lane >> 4;
  const int sw   = l15 & 7;

  const int cpx = gridDim.x >> 3;
  const int swz = (blockIdx.x & 7) * cpx + (blockIdx.x >> 3);
  const int bm  = (swz % MT) * 256;
  const int bn  = (swz / MT) * 192;
  const int nk  = K >> 6;

  const unsigned short* Abase = Ag + (size_t)bm * K;
  const unsigned short* Bbase = Bg + (size_t)bn * K;

#define SG(ldsbase, gbase, kt_, u_) do {                                        \
    const int _cid = (u_) * 512 + tid;                                          \
    const int _r = _cid >> 3, _ch = _cid & 7;                                   \
    gload_lds16((gbase) + (size_t)_r * K + (size_t)(kt_) * 64 +                 \
                    ((_ch ^ (_r & 7)) * 8),                                     \
                (void*)((char*)(ldsbase) + _cid * 16));                         \
  } while (0)
#define STAGE(abuf, bbuf, kt_) do {                                             \
    SG(abuf, Abase, kt_, 0); SG(abuf, Abase, kt_, 1);                           \
    SG(abuf, Abase, kt_, 2); SG(abuf, Abase, kt_, 3);                           \
    SG(bbuf, Bbase, kt_, 0); SG(bbuf, Bbase, kt_, 1);                           \
    SG(bbuf, Bbase, kt_, 2);                                                    \
  } while (0)

#define RD(base, r, kk)                                                          \
  (*(const bf16x8*)((const char*)(base) + (r) * 128 + ((((kk) * 4 + lg) ^ sw) * 16)))

#define MFMA24(afr, bfr) do {                                                    \
    _Pragma("unroll")                                                            \
    for (int _m = 0; _m < 4; ++_m)                                               \
      _Pragma("unroll")                                                          \
      for (int _n = 0; _n < 6; ++_n)                                             \
        acc[_m][_n] = __builtin_amdgcn_mfma_f32_16x16x32_bf16(                   \
            afr[_m], bfr[_n], acc[_m][_n], 0, 0, 0);                             \
  } while (0)

  f32x4 acc[4][6] = {};

  STAGE(As_[0], Bs_[0], 0);
  if (nk > 1) {
    STAGE(As_[1], Bs_[1], 1);
    asm volatile("s_waitcnt vmcnt(7)" ::: "memory");
  } else {
    asm volatile("s_waitcnt vmcnt(0)" ::: "memory");
  }
  SB;
  __builtin_amdgcn_s_barrier();

  for (int t = 0; t < nk; ++t) {
    const int cur = t & 1;
    const unsigned short* As = As_[cur];
    const unsigned short* Bs = Bs_[cur];
    bf16x8 a0[4], a1[4], b0[6], b1[6];

#pragma unroll
    for (int m = 0; m < 4; ++m) a0[m] = RD(As, wm * 64 + m * 16 + l15, 0);
#pragma unroll
    for (int n = 0; n < 6; ++n) b0[n] = RD(Bs, wn * 96 + n * 16 + l15, 0);
    SB;
#pragma unroll
    for (int m = 0; m < 4; ++m) a1[m] = RD(As, wm * 64 + m * 16 + l15, 1);
#pragma unroll
    for (int n = 0; n < 6; ++n) b1[n] = RD(Bs, wn * 96 + n * 16 + l15, 1);
    SB;
    asm volatile("s_waitcnt lgkmcnt(10)" ::: "memory");
    SB;
    __builtin_amdgcn_s_setprio(1);
    MFMA24(a0, b0);
    __builtin_amdgcn_s_setprio(0);
    SB;
    asm volatile("s_waitcnt lgkmcnt(0)" ::: "memory");
    SB;
    __builtin_amdgcn_s_barrier();
    if (t + 2 < nk) STAGE(As_[cur], Bs_[cur], t + 2);
    SB;
    __builtin_amdgcn_s_setprio(1);
    MFMA24(a1, b1);
    __builtin_amdgcn_s_setprio(0);
    if (t + 1 < nk) {
      if (t + 2 < nk) asm volatile("s_waitcnt vmcnt(7)" ::: "memory");
      else            asm volatile("s_waitcnt vmcnt(0)" ::: "memory");
      SB;
      __builtin_amdgcn_s_barrier();
    }
  }
#undef SG
#undef STAGE
#undef RD
#undef MFMA24

#pragma unroll
  for (int m = 0; m < 4; ++m)
#pragma unroll
    for (int i = 0; i < 4; ++i) {
      const int row = bm + wm * 64 + m * 16 + lg * 4 + i;
#pragma unroll
      for (int n = 0; n < 6; ++n)
        C[(size_t)row * N + bn + wn * 96 + n * 16 + l15] = f2bf(acc[m][n][i]);
    }
}

// ------- GEMM2: 256x128, (4M x 2N) waves, 2-cluster pipelined K-loop, f32 C
// A [M][K] bf16, B [N][K] bf16, C [M][N] f32. Wave tile 64x64, acc[4][4].
// Grid 8 x 32 = 256 blocks = 1 perfect CU round. STAGE = A 4 + B 2 = 6 gloads.
__global__ __launch_bounds__(512, 2) void gemm2_bt8(const unsigned short* __restrict__ Ag,
                                                    const unsigned short* __restrict__ Bg,
                                                    float* __restrict__ C,
                                                    int M, int N, int K, int MT) {
  __shared__ unsigned short As_[2][256 * 64];   // 32 KB x2
  __shared__ unsigned short Bs_[2][128 * 64];   // 16 KB x2  (96 KB total)
  const int tid  = threadIdx.x;
  const int lane = tid & 63;
  const int w    = tid >> 6;
  const int wm   = w & 3;         // 0..3  (M quarter, 64 rows)
  const int wn   = w >> 2;        // 0..1  (N half, 64 cols)
  const int l15  = lane & 15;
  const int lg   = lane >> 4;
  const int sw   = l15 & 7;

  const int cpx = gridDim.x >> 3;
  const int swz = (blockIdx.x & 7) * cpx + (blockIdx.x >> 3);
  const int bm  = (swz % MT) * 256;
  const int bn  = (swz / MT) * 128;
  const int nk  = K >> 6;

  const unsigned short* Abase = Ag + (size_t)bm * K;
  const unsigned short* Bbase = Bg + (size_t)bn * K;

#define SG(ldsbase, gbase, kt_, u_) do {                                        \
    const int _cid = (u_) * 512 + tid;                                          \
    const int _r = _cid >> 3, _ch = _cid & 7;                                   \
    gload_lds16((gbase) + (size_t)_r * K + (size_t)(kt_) * 64 +                 \
                    ((_ch ^ (_r & 7)) * 8),                                     \
                (void*)((char*)(ldsbase) + _cid * 16));                         \
  } while (0)
#define STAGE(abuf, bbuf, kt_) do {                                             \
    SG(abuf, Abase, kt_, 0); SG(abuf, Abase, kt_, 1);                           \
    SG(abuf, Abase, kt_, 2); SG(abuf, Abase, kt_, 3);                           \
    SG(bbuf, Bbase, kt_, 0); SG(bbuf, Bbase, kt_, 1);                           \
  } while (0)

#define RD(base, r, kk)                                                          \
  (*(const bf16x8*)((const char*)(base) + (r) * 128 + ((((kk) * 4 + lg) ^ sw) * 16)))

#define MFMA16(afr, bfr) do {                                                    \
    _Pragma("unroll")                                                            \
    for (int _m = 0; _m < 4; ++_m)                                               \
      _Pragma("unroll")                                                          \
      for (int _n = 0; _n < 4; ++_n)                                             \
        acc[_m][_n] = __builtin_amdgcn_mfma_f32_16x16x32_bf16(                   \
            afr[_m], bfr[_n], acc[_m][_n], 0, 0, 0);                             \
  } while (0)

  f32x4 acc[4][4] = {};

  STAGE(As_[0], Bs_[0], 0);
  if (nk > 1) {
    STAGE(As_[1], Bs_[1], 1);
    asm volatile("s_waitcnt vmcnt(6)" ::: "memory");
  } else {
    asm volatile("s_waitcnt vmcnt(0)" ::: "memory");
  }
  SB;
  __builtin_amdgcn_s_barrier();

  for (int t = 0; t < nk; ++t) {
    const int cur = t & 1;
    const unsigned short* As = As_[cur];
    const unsigned short* Bs = Bs_[cur];
    bf16x8 a0[4], a1[4], b0[4], b1[4];

#pragma unroll
    for (int m = 0; m < 4; ++m) a0[m] = RD(As, wm * 64 + m * 16 + l15, 0);
#pragma unroll
    for (int n = 0; n < 4; ++n) b0[n] = RD(Bs, wn * 64 + n * 16 + l15, 0);
    SB;
#pragma unroll
    for (int m = 0; m < 4; ++m) a1[m] = RD(As, wm * 64 + m * 16 + l15, 1);
#pragma unroll
    for (int n = 0; n < 4; ++n) b1[n] = RD(Bs, wn * 64 + n * 16 + l15, 1);
    SB;
    asm volatile("s_waitcnt lgkmcnt(8)" ::: "memory");
    SB;
    __builtin_amdgcn_s_setprio(1);
    MFMA16(a0, b0);
    __builtin_amdgcn_s_setprio(0);
    SB;
    asm volatile("s_waitcnt lgkmcnt(0)" ::: "memory");
    SB;
    __builtin_amdgcn_s_barrier();
    if (t + 2 < nk) STAGE(As_[cur], Bs_[cur], t + 2);
    SB;
    __builtin_amdgcn_s_setprio(1);
    MFMA16(a1, b1);
    __builtin_amdgcn_s_setprio(0);
    if (t + 1 < nk) {
      if (t + 2 < nk) asm volatile("s_waitcnt vmcnt(6)" ::: "memory");
      else            asm volatile("s_waitcnt vmcnt(0)" ::: "memory");
      SB;
      __builtin_amdgcn_s_barrier();
    }
  }
#undef SG
#undef STAGE
#undef RD
#undef MFMA16

#pragma unroll
  for (int m = 0; m < 4; ++m)
#pragma unroll
    for (int i = 0; i < 4; ++i) {
      const int row = bm + wm * 64 + m * 16 + lg * 4 + i;
#pragma unroll
      for (int n = 0; n < 4; ++n)
        C[(size_t)row * N + bn + wn * 64 + n * 16 + l15] = acc[m][n][i];
    }
}

// ---------------------------------------- LayerNorm + RoPE + split/cast kernel
__global__ __launch_bounds__(256) void norm_rope(const unsigned short* __restrict__ qkv,
                                                 const float* __restrict__ qw,
                                                 const float* __restrict__ qb,
                                                 const float* __restrict__ kw,
                                                 const float* __restrict__ kb,
                                                 unsigned short* __restrict__ q,
                                                 unsigned short* __restrict__ k) {
  const int t    = blockIdx.x;
  const int tid  = threadIdx.x;
  const int lane = tid & 63;
  const int w    = tid >> 6;
  const float invf = exp2f(-(float)lane * (13.287712379549449f / 64.0f)); // 10000^(-lane/64)
  const float ang  = (float)t * invf;
  const float c = cosf(ang), s = sinf(ang);
  const unsigned short* row = qkv + (size_t)t * QKVW;

#pragma unroll 1
  for (int sel = 0; sel < 2; ++sel) {
    const unsigned short* src = row + sel * HID;
    const float* wgt = sel ? kw : qw;
    const float* bia = sel ? kb : qb;
    unsigned short* dst = sel ? k : q;
    const float oscale = sel ? 1.0f : QSCALE;
    for (int h = w; h < NH; h += 4) {
      const unsigned short* x = src + h * HD;
      float x1 = bf2f(x[lane]), x2 = bf2f(x[lane + 64]);
      float sum = x1 + x2, ss = x1 * x1 + x2 * x2;
#pragma unroll
      for (int m = 1; m < 64; m <<= 1) {
        sum += __shfl_xor(sum, m, 64);
        ss  += __shfl_xor(ss, m, 64);
      }
      const float mu  = sum * (1.0f / 128.0f);
      const float var = ss * (1.0f / 128.0f) - mu * mu;
      const float r   = rsqrtf(var + 1e-5f);
      const float n1  = (x1 - mu) * r * wgt[h * HD + lane]      + bia[h * HD + lane];
      const float n2  = (x2 - mu) * r * wgt[h * HD + lane + 64] + bia[h * HD + lane + 64];
      const float o1  = (n1 * c - n2 * s) * oscale;
      const float o2  = (n2 * c + n1 * s) * oscale;
      dst[(size_t)t * HID + h * HD + lane]      = f2bf(o1);
      dst[(size_t)t * HID + h * HD + lane + 64] = f2bf(o2);
    }
  }
}

// --------------------------- V transpose: [T][stride=QKVW] slice ->[H][D][T]
__global__ __launch_bounds__(256) void transpose_v(const unsigned short* __restrict__ v,
                                                   unsigned short* __restrict__ vt) {
  __shared__ unsigned short tile[64][65];
  const int h  = blockIdx.z;
  const int tt = blockIdx.x * 64;
  const int dd = blockIdx.y * 64;
  const int tid = threadIdx.x;
#pragma unroll
  for (int p = 0; p < 4; ++p) {
    int idx = p * 256 + tid;
    int r = idx >> 4, c4 = idx & 15;
    ushort4 val = *(const ushort4*)&v[(size_t)(tt + r) * QKVW + h * HD + dd + c4 * 4];
    tile[r][c4 * 4 + 0] = val.x;
    tile[r][c4 * 4 + 1] = val.y;
    tile[r][c4 * 4 + 2] = val.z;
    tile[r][c4 * 4 + 3] = val.w;
  }
  __syncthreads();
#pragma unroll
  for (int p = 0; p < 4; ++p) {
    int idx = p * 256 + tid;
    int r = idx >> 4, c4 = idx & 15;
    ushort4 o;
    o.x = tile[c4 * 4 + 0][r];
    o.y = tile[c4 * 4 + 1][r];
    o.z = tile[c4 * 4 + 2][r];
    o.w = tile[c4 * 4 + 3][r];
    *(ushort4*)&vt[((size_t)h * HD + dd + r) * T_SEQ + tt + c4 * 4] = o;
  }
}

// -------------------------------------------------- causal flash attention
// R10 version: QBLK=64, 4 waves x 16 q-rows, KVBLK=64, dbuf swizzled LDS,
// pairing (b, 31-b), 512 blocks (2 blocks/CU — the occupancy that R11 lost).
__global__ __launch_bounds__(256) void attn_fwd(const unsigned short* __restrict__ Q,
                                                const unsigned short* __restrict__ K,
                                                const unsigned short* __restrict__ VT,
                                                unsigned short* __restrict__ O) {
  __shared__ unsigned short Ks[2][64 * 128];  // [kv][d], swizzled
  __shared__ unsigned short Vs[2][128 * 64];  // [d][kv], swizzled
  __shared__ unsigned short Ps[4][16 * 64];   // per-wave [qrow][kv], swizzled
  const int h    = blockIdx.y;
  const int pair = blockIdx.x;                 // 0..15
  const int tid  = threadIdx.x;
  const int lane = tid & 63;
  const int w    = tid >> 6;
  const int l15  = lane & 15;
  const int lg   = lane >> 4;
  const int sw   = l15 & 7;

#pragma unroll 1
  for (int half = 0; half < 2; ++half) {
    const int qt   = half ? (31 - pair) : pair;   // 64-row q-tile index
    const int qrow = qt * 64 + w * 16;

    bf16x8 qf[4];
#pragma unroll
    for (int kk = 0; kk < 4; ++kk)
      qf[kk] = *(const bf16x8*)&Q[(size_t)(qrow + l15) * HID + h * HD + kk * 32 + lg * 8];

    f32x4 o[8] = {};
    float mrow[4], lrow[4];
#pragma unroll
    for (int i = 0; i < 4; ++i) { mrow[i] = -1e30f; lrow[i] = 0.0f; }

    const int nkt = qt + 1;

    // prologue: stage kv-tile 0 into buffer 0 (swizzled source, linear LDS dest)
    {
#pragma unroll
      for (int p = 0; p < 4; ++p) {
        const int c  = p * 256 + tid;
        const int kr = c >> 4, kc = c & 15;
        gload_lds16(&K[(size_t)kr * HID + h * HD + ((kc ^ (kr & 7)) * 8)],
                    &Ks[0][(p * 256 + w * 64) * 8]);
        const int vr = c >> 3, vc = c & 7;
        gload_lds16(&VT[((size_t)h * HD + vr) * T_SEQ + ((vc ^ (vr & 7)) * 8)],
                    &Vs[0][(p * 256 + w * 64) * 8]);
      }
    }
    __syncthreads();

#pragma unroll 1
    for (int kt = 0; kt < nkt; ++kt) {
      const int cur = kt & 1;
      if (kt + 1 < nkt) {
        const int k0 = (kt + 1) * 64;
#pragma unroll
        for (int p = 0; p < 4; ++p) {
          const int c  = p * 256 + tid;
          const int kr = c >> 4, kc = c & 15;
          gload_lds16(&K[(size_t)(k0 + kr) * HID + h * HD + ((kc ^ (kr & 7)) * 8)],
                      &Ks[cur ^ 1][(p * 256 + w * 64) * 8]);
          const int vr = c >> 3, vc = c & 7;
          gload_lds16(&VT[((size_t)h * HD + vr) * T_SEQ + k0 + ((vc ^ (vr & 7)) * 8)],
                      &Vs[cur ^ 1][(p * 256 + w * 64) * 8]);
        }
      }
      const unsigned short* ksb = Ks[cur];
      const unsigned short* vsb = Vs[cur];

      // QK^T: S[q=16][kv=64], swizzled K reads (conflict-free)
      f32x4 sfr[4] = {};
#pragma unroll
      for (int n = 0; n < 4; ++n)
#pragma unroll
        for (int kk = 0; kk < 4; ++kk) {
          bf16x8 kf = *(const bf16x8*)&ksb[(n * 16 + l15) * 128 + ((kk * 4 + lg) ^ sw) * 8];
          sfr[n] = __builtin_amdgcn_mfma_f32_16x16x32_bf16(qf[kk], kf, sfr[n], 0, 0, 0);
        }

      if (kt == qt) {  // diagonal tile: causal mask (within-tile coords)
#pragma unroll
        for (int n = 0; n < 4; ++n)
#pragma unroll
          for (int i = 0; i < 4; ++i)
            if (n * 16 + l15 > w * 16 + lg * 4 + i) sfr[n][i] = -1e30f;
      }

      // online softmax (base-2 domain; scale folded into Q)
      float escale[4];
#pragma unroll
      for (int i = 0; i < 4; ++i) {
        float mx = fmaxf(fmaxf(sfr[0][i], sfr[1][i]), fmaxf(sfr[2][i], sfr[3][i]));
        mx = fmaxf(mx, __shfl_xor(mx, 1, 64));
        mx = fmaxf(mx, __shfl_xor(mx, 2, 64));
        mx = fmaxf(mx, __shfl_xor(mx, 4, 64));
        mx = fmaxf(mx, __shfl_xor(mx, 8, 64));
        const float mnew = fmaxf(mrow[i], mx);
        escale[i] = exp2f(mrow[i] - mnew);
        mrow[i] = mnew;
        const int prow = lg * 4 + i;
        float rs = 0.0f;
#pragma unroll
        for (int n = 0; n < 4; ++n) {
          const float p = exp2f(sfr[n][i] - mnew);
          rs += p;
          Ps[w][prow * 64 + (((2 * n + (l15 >> 3)) ^ (prow & 7)) * 8) + sw] = f2bf(p);
        }
        rs += __shfl_xor(rs, 1, 64);
        rs += __shfl_xor(rs, 2, 64);
        rs += __shfl_xor(rs, 4, 64);
        rs += __shfl_xor(rs, 8, 64);
        lrow[i] = lrow[i] * escale[i] + rs;
      }
#pragma unroll
      for (int f = 0; f < 8; ++f)
#pragma unroll
        for (int i = 0; i < 4; ++i) o[f][i] *= escale[i];

      // P is wave-private: no barrier, just drain LDS writes
      asm volatile("s_waitcnt lgkmcnt(0)" ::: "memory");
      __builtin_amdgcn_sched_barrier(0);

      bf16x8 pf[2];
#pragma unroll
      for (int kk = 0; kk < 2; ++kk)
        pf[kk] = *(const bf16x8*)&Ps[w][l15 * 64 + ((kk * 4 + lg) ^ sw) * 8];
#pragma unroll
      for (int f = 0; f < 8; ++f)
#pragma unroll
        for (int kk = 0; kk < 2; ++kk) {
          bf16x8 vf = *(const bf16x8*)&vsb[(f * 16 + l15) * 64 + ((kk * 4 + lg) ^ sw) * 8];
          o[f] = __builtin_amdgcn_mfma_f32_16x16x32_bf16(pf[kk], vf, o[f], 0, 0, 0);
        }

      __syncthreads();  // reads of buf[cur] done; stage into buf[cur^1] drained
    }

#pragma unroll
    for (int i = 0; i < 4; ++i) {
      const float inv = 1.0f / lrow[i];
      const int trow = qrow + lg * 4 + i;
#pragma unroll
      for (int f = 0; f < 8; ++f)
        O[(size_t)trow * HID + h * HD + f * 16 + l15] = f2bf(o[f][i] * inv);
    }
  }
}

// ------------------------------------------------------------------- launch
extern "C" void kernel_launch(void* const* d_in, const int* in_sizes, int n_in,
                              void* d_out, int out_size, void* d_ws, size_t ws_size,
                              hipStream_t stream) {
  const float* hidden = (const float*)d_in[1];
  const float* w_qkv  = (const float*)d_in[2];
  const float* w_o    = (const float*)d_in[3];
  const float* qw     = (const float*)d_in[4];
  const float* qb     = (const float*)d_in[5];
  const float* kw     = (const float*)d_in[6];
  const float* kb     = (const float*)d_in[7];

  char* ws = (char*)d_ws;
  // region A (100663296 B): w_qkv_bf16 during GEMM1; then attn_bf16 + w_o_bf16
  unsigned short* wqkv_bf = (unsigned short*)(ws + 0);
  unsigned short* attn_bf = (unsigned short*)(ws + 0);
  unsigned short* wo_bf   = (unsigned short*)(ws + 16777216);
  // region B (16777216 B): hidden_bf16 during GEMM1; then vt
  unsigned short* hid_bf  = (unsigned short*)(ws + 100663296);
  unsigned short* vt_bf   = (unsigned short*)(ws + 100663296);
  // region C: qkv bf16 [T][12288] (50331648 B); V slice stays in place
  unsigned short* qkv_bf  = (unsigned short*)(ws + 117440512);
  // region D: q,k bf16
  unsigned short* q_bf    = (unsigned short*)(ws + 167772160);
  unsigned short* k_bf    = (unsigned short*)(ws + 184549376);

  cast_bf16<<<2048, 256, 0, stream>>>(hidden, hid_bf, (T_SEQ * HID) / 4);
  cast_bf16<<<2048, 256, 0, stream>>>(w_qkv, wqkv_bf, (QKVW * HID) / 4);
  // GEMM1: M=2048 (MT=8), N=12288 -> 8 x 64 = 512 blocks = 2 perfect CU rounds
  gemm_bt8<<<512, 512, 0, stream>>>(hid_bf, wqkv_bf, qkv_bf, T_SEQ, QKVW, HID, 8);
  cast_bf16<<<2048, 256, 0, stream>>>(w_o, wo_bf, (HID * HID) / 4);
  norm_rope<<<T_SEQ, 256, 0, stream>>>(qkv_bf, qw, qb, kw, kb, q_bf, k_bf);
  transpose_v<<<dim3(T_SEQ / 64, HD / 64, NH), 256, 0, stream>>>(qkv_bf + 2 * HID, vt_bf);
  // attn: QBLK=64, pairing (b, 31-b) -> 16 x 32 = 512 blocks (2/CU)
  attn_fwd<<<dim3(16, NH), 256, 0, stream>>>(q_bf, k_bf, vt_bf, attn_bf);
  // GEMM2: 2-cluster pipelined, M=2048 (MT=8), N=4096 -> 256 blocks (1 round)
  gemm2_bt8<<<256, 512, 0, stream>>>(attn_bf, wo_bf, (float*)d_out, T_SEQ, HID, HID, 8);
}